// Round 13
// baseline (901.778 us; speedup 1.0000x reference)
//
#include <hip/hip_runtime.h>
#include <hip/hip_bf16.h>
#include <math.h>

#define NN 512
#define ROWS (NN * NN)
#define HH 512

#define NB 16                 // coop_post blocks
#define NT 512                // threads per block
#define RPB 32                // rows per block

// ws layout (float offsets)
#define WS_EMB   0                       // [4096] emb partials
#define WS_W1F   4096                    // [131072] = 262144 bf16 (fragment-major W1)
#define WS_XCH   (WS_W1F + 131072)       // u64 exchange region (aligned, 8B granules):
//   colp  [16*512] u64   : +0
//   uslot [2*512]  u64   : +8192
//   xslot [2*512*3] u64  : +9216
//   total 12288 u64 = 98304 B

typedef __attribute__((ext_vector_type(8))) short bf16x8;
typedef __attribute__((ext_vector_type(4))) float f32x4;

#define AGENT __HIP_MEMORY_SCOPE_AGENT

__device__ __forceinline__ short f2bf(float f) {   // RTNE (prep only)
    union { float f; unsigned u; } v; v.f = f;
    unsigned r = v.u + 0x7fffu + ((v.u >> 16) & 1u);
    return (short)(r >> 16);
}

__device__ __forceinline__ unsigned pack_bf2(float lo, float hi) {
    return __builtin_amdgcn_perm(__float_as_uint(hi), __float_as_uint(lo),
                                 0x07060302u);
}

__device__ __forceinline__ float softplus_f(float x) {
    return fmaxf(x, 0.0f) + log1pf(expf(-fabsf(x)));
}

// ---- self-validating dataflow words: (gen<<32) | float_bits ----------------
__device__ __forceinline__ void pub64(unsigned long long* p, float val, int gen) {
    unsigned long long v = ((unsigned long long)(unsigned)gen << 32) |
                           (unsigned long long)__float_as_uint(val);
    __hip_atomic_store(p, v, __ATOMIC_RELAXED, AGENT);
}
__device__ __forceinline__ float poll64(const unsigned long long* p, int gen) {
    unsigned long long v;
    for (;;) {
        v = __hip_atomic_load(p, __ATOMIC_RELAXED, AGENT);
        if ((int)(v >> 32) == gen) break;
        __builtin_amdgcn_s_sleep(1);
    }
    return __uint_as_float((unsigned)v);
}

// ---------------------------------------------------------------------------
// W1 (fp32 [k][n]) -> W1F fragment-major bf16 (wave B-frag = 1KB contiguous)
// ---------------------------------------------------------------------------
__global__ void w1f_prep(const float* __restrict__ W1, short* __restrict__ W1F)
{
    const int c = blockIdx.x * 256 + threadIdx.x;   // 0..32767
    const int lane = c & 63;
    const int g = c >> 6;
    const int colg = g & 31;
    const int kc = g >> 5;
    const int col = colg * 16 + (lane & 15);
    const int kb = kc * 32 + (lane >> 4) * 8;
    bf16x8 w;
    #pragma unroll
    for (int j = 0; j < 8; j++)
        w[j] = f2bf(W1[(size_t)(kb + j) * HH + col]);
    *(bf16x8*)(W1F + (size_t)c * 8) = w;
}

// ---------------------------------------------------------------------------
// Phase 1 (round-12 proven): h = relu(A@W1+b1) via bf16 MFMA; fused epilogue
// ---------------------------------------------------------------------------
__global__ __launch_bounds__(512, 4) void fused_mlp(
    const float* __restrict__ A, const short* __restrict__ W1F,
    const float* __restrict__ b1, const float* __restrict__ W2,
    const float* __restrict__ b2, float* __restrict__ outD,
    float* __restrict__ outW, float* __restrict__ embpart)
{
    __shared__ short As[2][64 * 40];
    __shared__ float sp0[8][64], sp1[8][64];
    __shared__ float semb[8];

    const int tid = threadIdx.x;
    const int lane = tid & 63;
    const int wc = tid >> 6;
    const int l15 = lane & 15;
    const int l4 = lane >> 4;
    const int row0 = blockIdx.x * 64;

    f32x4 acc[4][4];
    #pragma unroll
    for (int m = 0; m < 4; m++)
        #pragma unroll
        for (int n = 0; n < 4; n++) {
            f32x4 z = {0.0f, 0.0f, 0.0f, 0.0f};
            acc[m][n] = z;
        }

    const int sr = tid >> 3;
    const int sk4 = (tid & 7) * 4;
    const float* agp = A + (size_t)(row0 + sr) * HH + sk4;
    const short* bfp = W1F + ((size_t)(wc * 4) * 64 + lane) * 8;

    {
        float4 a0 = *(const float4*)agp;
        uint2 w = {pack_bf2(a0.x, a0.y), pack_bf2(a0.z, a0.w)};
        *(uint2*)&As[0][sr * 40 + sk4] = w;
    }
    bf16x8 bfr[4];
    #pragma unroll
    for (int n = 0; n < 4; n++)
        bfr[n] = *(const bf16x8*)(bfp + n * 512);
    __syncthreads();

    int cur = 0;
    #pragma unroll 1
    for (int s = 0; s < 16; s++) {
        const int k0 = s * 32;
        bf16x8 bfrN[4];
        if (s < 15) {
            #pragma unroll
            for (int n = 0; n < 4; n++)
                bfrN[n] = *(const bf16x8*)(bfp + (s + 1) * 16384 + n * 512);
        }
        float4 pv;
        if (s < 15) pv = *(const float4*)(agp + k0 + 32);
        bf16x8 af[4];
        #pragma unroll
        for (int m = 0; m < 4; m++)
            af[m] = *(const bf16x8*)&As[cur][(m * 16 + l15) * 40 + l4 * 8];
        #pragma unroll
        for (int m = 0; m < 4; m++)
            #pragma unroll
            for (int n = 0; n < 4; n++)
                acc[m][n] = __builtin_amdgcn_mfma_f32_16x16x32_bf16(
                    af[m], bfr[n], acc[m][n], 0, 0, 0);
        if (s < 15) {
            uint2 w = {pack_bf2(pv.x, pv.y), pack_bf2(pv.z, pv.w)};
            *(uint2*)&As[cur ^ 1][sr * 40 + sk4] = w;
            #pragma unroll
            for (int n = 0; n < 4; n++) bfr[n] = bfrN[n];
        }
        __syncthreads();
        cur ^= 1;
    }

    float b1c[4], w20[4], w21[4];
    #pragma unroll
    for (int n = 0; n < 4; n++) {
        int col = wc * 64 + n * 16 + l15;
        b1c[n] = b1[col];
        w20[n] = W2[col * 2 + 0];
        w21[n] = W2[col * 2 + 1];
    }
    float embl = 0.0f;
    #pragma unroll
    for (int m = 0; m < 4; m++) {
        #pragma unroll
        for (int j = 0; j < 4; j++) {
            float s0 = 0.0f, s1 = 0.0f;
            #pragma unroll
            for (int n = 0; n < 4; n++) {
                float h = fmaxf(acc[m][n][j] + b1c[n], 0.0f);
                s0 = fmaf(h, w20[n], s0);
                s1 = fmaf(h, w21[n], s1);
                embl += h;
            }
            #pragma unroll
            for (int st = 1; st < 16; st <<= 1) {
                s0 += __shfl_xor(s0, st);
                s1 += __shfl_xor(s1, st);
            }
            if (l15 == 0) {
                int row = m * 16 + l4 * 4 + j;
                sp0[wc][row] = s0;
                sp1[wc][row] = s1;
            }
        }
    }
    #pragma unroll
    for (int st = 1; st < 64; st <<= 1) embl += __shfl_xor(embl, st);
    if (lane == 0) semb[wc] = embl;
    __syncthreads();
    if (tid < 64) {
        int gr = row0 + tid;
        float p0 = b2[0], p1 = b2[1];
        #pragma unroll
        for (int w = 0; w < 8; w++) { p0 += sp0[w][tid]; p1 += sp1[w][tid]; }
        int di = gr >> 9, dj = gr & 511;
        outD[gr] = (di == dj) ? 0.0f : softplus_f(p0);
        outW[gr] = softplus_f(p1);
    }
    if (tid == 0) {
        float e = 0.0f;
        #pragma unroll
        for (int w = 0; w < 8; w++) e += semb[w];
        embpart[blockIdx.x] = e;
    }
}

__device__ __forceinline__ void block_sum5(float* v, float (*red)[8], int tid) {
    #pragma unroll
    for (int s = 1; s < 64; s <<= 1)
        #pragma unroll
        for (int q = 0; q < 5; q++) v[q] += __shfl_xor(v[q], s);
    if ((tid & 63) == 0)
        #pragma unroll
        for (int q = 0; q < 5; q++) red[q][tid >> 6] = v[q];
    __syncthreads();
    #pragma unroll
    for (int q = 0; q < 5; q++) {
        float r = 0.0f;
        #pragma unroll
        for (int i = 0; i < 8; i++) r += red[q][i];
        v[q] = r;
    }
    __syncthreads();
}

__device__ __forceinline__ float block_sum1(float v, float (*red)[8], int tid) {
    #pragma unroll
    for (int s = 1; s < 64; s <<= 1) v += __shfl_xor(v, s);
    if ((tid & 63) == 0) red[0][tid >> 6] = v;
    __syncthreads();
    float r = 0.0f;
    #pragma unroll
    for (int i = 0; i < 8; i++) r += red[0][i];
    __syncthreads();
    return r;
}

// ---------------------------------------------------------------------------
// Phases 2-4: NB=16 x NT=512, RPB=32 rows/block. ZERO barriers:
// all cross-block exchange via self-validating (gen|float) dataflow words.
// ---------------------------------------------------------------------------
__global__ __launch_bounds__(512, 1) void coop_post(
    const float* __restrict__ Dg, const float* __restrict__ Wg,
    const float* __restrict__ noise, const float* __restrict__ uinit,
    float* __restrict__ outE, float* __restrict__ outX,
    float* __restrict__ ws)
{
    __shared__ float Dl[RPB][516];     // phase3: D rows; phase4: S2 (in-place)
    __shared__ float S1[RPB][516];
    __shared__ float Xl[512][4];
    __shared__ float ul[512];
    __shared__ float upl[3][512];
    __shared__ float cm[512];
    __shared__ float rm[RPB];
    __shared__ float red5[5][8];

    const int tid = threadIdx.x;
    const int bid = blockIdx.x;
    const int r0 = bid * RPB;

    float* embpart = ws + WS_EMB;
    unsigned long long* xch = (unsigned long long*)(ws + WS_XCH);
    unsigned long long* colp  = xch;            // [16*512]
    unsigned long long* uslot = xch + 8192;     // [2*512]
    unsigned long long* xslot = xch + 9216;     // [2*512*3]

    // ---- phase 2a: load D rows, row means, publish column partial sums
    for (int idx = tid; idx < RPB * 512; idx += NT) {
        int r = idx >> 9, c = idx & 511;
        Dl[r][c] = Dg[(size_t)(r0 + r) * NN + c];
    }
    __syncthreads();
    const int mr = tid >> 4;           // 0..31
    const int ml = tid & 15;
    {
        float s = 0.0f;
        for (int j = ml; j < 512; j += 16) s += Dl[mr][j];
        #pragma unroll
        for (int st = 1; st < 16; st <<= 1) s += __shfl_xor(s, st);
        if (ml == 0) rm[mr] = s * (1.0f / 512.0f);
    }
    {
        float s = 0.0f;
        #pragma unroll
        for (int r = 0; r < RPB; r++) s += Dl[r][tid];
        pub64(&colp[bid * 512 + tid], s, 1);
    }

    // ---- phase 2b: gather column means (dataflow); emb total (block 0)
    {
        float s = 0.0f;
        #pragma unroll 1
        for (int p = 0; p < NB; p++)
            s += poll64(&colp[p * 512 + tid], 1);
        cm[tid] = s * (1.0f / 512.0f);
    }
    if (bid == 0) {
        float s = 0.0f;
        for (int i = tid; i < ROWS / 64; i += NT) s += embpart[i];
        s = block_sum1(s, red5, tid);
        if (tid == 0) outE[0] = s;
    }
    __syncthreads();
    float Dmean = block_sum1(cm[tid], red5, tid) * (1.0f / 512.0f);

    // ---- phase 3: power iteration, dataflow u exchange
    #pragma unroll 1
    for (int rank = 0; rank < 3; rank++) {
        #pragma unroll 1
        for (int step = 0; step < 10; step++) {
            const int s3 = rank * 10 + step;
            if (step == 0) {
                ul[tid] = uinit[tid * 3 + rank];
            } else {
                ul[tid] = poll64(&uslot[((s3 - 1) & 1) * 512 + tid], s3);
            }
            __syncthreads();
            float u = ul[tid];
            float v[5];
            v[0] = u * u;
            v[1] = u;
            v[2] = cm[tid] * u;
            v[3] = (rank > 0) ? upl[0][tid] * u : 0.0f;
            v[4] = (rank > 1) ? upl[1][tid] * u : 0.0f;
            block_sum5(v, red5, tid);
            float inv = 1.0f / fmaxf(sqrtf(v[0]), 0.001f);
            float S = v[1] * inv, dr = v[2] * inv;
            float d0s = v[3] * inv, d1s = v[4] * inv;
            float a = 0.0f;
            for (int j = ml; j < 512; j += 16) a = fmaf(Dl[mr][j], ul[j], a);
            #pragma unroll
            for (int st = 1; st < 16; st <<= 1) a += __shfl_xor(a, st);
            if (ml == 0) {
                float bvv = -0.5f * (a * inv - dr - rm[mr] * S + Dmean * S);
                if (rank > 0) bvv -= d0s * upl[0][r0 + mr];
                if (rank > 1) bvv -= d1s * upl[1][r0 + mr];
                pub64(&uslot[(s3 & 1) * 512 + r0 + mr], bvv, s3 + 1);
            }
        }
        // finalize rank: read the step-9 publish, fully local after that
        {
            const int s3l = rank * 10 + 9;
            float u = poll64(&uslot[(s3l & 1) * 512 + tid], s3l + 1);
            float eig2 = block_sum1(u * u, red5, tid);
            float scl = sqrtf(sqrtf(eig2 + 0.01f));
            upl[rank][tid] = u * scl;
            Xl[tid][rank] = fmaf(u, scl, noise[tid * 3 + rank]);
            if (rank == 0) Xl[tid][3] = 0.0f;
            __syncthreads();
        }
    }

    // ---- phase 4 prep: S1 = W+W^T; S2 = W.D + (W.D)^T  (S2 overwrites Dl)
    for (int idx = tid; idx < RPB * 512; idx += NT) {
        int r = idx >> 9, j = idx & 511;
        int gr = r0 + r;
        float wr = Wg[(size_t)gr * NN + j];
        float wc = Wg[(size_t)j * NN + gr];
        float dc = Dg[(size_t)j * NN + gr];
        float d  = Dl[r][j];
        S1[r][j] = wr + wc;
        Dl[r][j] = fmaf(wr, d, wc * dc);   // S2
    }
    __syncthreads();

    // ---- phase 4: 100 gradient-flow steps, dataflow X exchange
    #pragma unroll 1
    for (int t = 0; t < 100; t++) {
        if (t > 0) {
            // gather X(t): 3 self-validating words per row, issued in parallel
            const unsigned long long* xs = xslot + ((t - 1) & 1) * 1536 + tid * 3;
            unsigned long long w0, w1, w2;
            for (;;) {
                w0 = __hip_atomic_load(&xs[0], __ATOMIC_RELAXED, AGENT);
                w1 = __hip_atomic_load(&xs[1], __ATOMIC_RELAXED, AGENT);
                w2 = __hip_atomic_load(&xs[2], __ATOMIC_RELAXED, AGENT);
                if ((int)(w0 >> 32) == t && (int)(w1 >> 32) == t &&
                    (int)(w2 >> 32) == t) break;
                __builtin_amdgcn_s_sleep(1);
            }
            Xl[tid][0] = __uint_as_float((unsigned)w0);
            Xl[tid][1] = __uint_as_float((unsigned)w1);
            Xl[tid][2] = __uint_as_float((unsigned)w2);
            Xl[tid][3] = 0.0f;
            __syncthreads();
        }
        float xr0 = Xl[r0 + mr][0], xr1 = Xl[r0 + mr][1], xr2 = Xl[r0 + mr][2];
        float g0 = 0, g1 = 0, g2 = 0;
        for (int j = ml; j < 512; j += 16) {
            float dx0 = xr0 - Xl[j][0];
            float dx1 = xr1 - Xl[j][1];
            float dx2 = xr2 - Xl[j][2];
            float d2 = fmaf(dx0, dx0, fmaf(dx1, dx1, fmaf(dx2, dx2, 0.01f)));
            float ri = rsqrtf(d2);
            float coef = fmaf(Dl[mr][j], ri, -S1[mr][j]);
            g0 = fmaf(coef, dx0, g0);
            g1 = fmaf(coef, dx1, g1);
            g2 = fmaf(coef, dx2, g2);
        }
        #pragma unroll
        for (int st = 1; st < 16; st <<= 1) {
            g0 += __shfl_xor(g0, st);
            g1 += __shfl_xor(g1, st);
            g2 += __shfl_xor(g2, st);
        }
        if (ml == 0) {
            float dX0 = 0.2f * g0, dX1 = 0.2f * g1, dX2 = 0.2f * g2;
            float sp = sqrtf(fmaf(dX0, dX0, fmaf(dX1, dX1, fmaf(dX2, dX2, 0.001f))));
            float alpha = 0.1f + 4.9f * (float)(100 - t) * 0.01f;
            float scal = alpha * tanhf(sp / alpha) / sp;
            float n0 = fmaf(dX0, scal, xr0);
            float n1 = fmaf(dX1, scal, xr1);
            float n2 = fmaf(dX2, scal, xr2);
            int gr = r0 + mr;
            if (t == 99) {
                outX[gr * 3 + 0] = n0;
                outX[gr * 3 + 1] = n1;
                outX[gr * 3 + 2] = n2;
            } else {
                unsigned long long* xd = xslot + (t & 1) * 1536 + gr * 3;
                pub64(&xd[0], n0, t + 1);
                pub64(&xd[1], n1, t + 1);
                pub64(&xd[2], n2, t + 1);
            }
        }
    }
}

extern "C" void kernel_launch(void* const* d_in, const int* in_sizes, int n_in,
                              void* d_out, int out_size, void* d_ws, size_t ws_size,
                              hipStream_t stream)
{
    const float* A     = (const float*)d_in[0];
    const float* W1    = (const float*)d_in[1];
    const float* b1    = (const float*)d_in[2];
    const float* W2    = (const float*)d_in[3];
    const float* b2    = (const float*)d_in[4];
    const float* noise = (const float*)d_in[5];
    const float* uinit = (const float*)d_in[6];

    float* out  = (float*)d_out;
    float* outD = out;
    float* outW = out + ROWS;
    float* outE = out + 2 * ROWS;
    float* outX = out + 2 * ROWS + 1;
    float* ws   = (float*)d_ws;
    short* W1F  = (short*)(ws + WS_W1F);

    // reset dataflow exchange region each call (gen=0 never matches)
    (void)hipMemsetAsync((char*)d_ws + (size_t)WS_XCH * sizeof(float), 0,
                         12288 * sizeof(unsigned long long), stream);

    hipLaunchKernelGGL(w1f_prep, dim3(128), dim3(256), 0, stream, W1, W1F);

    hipLaunchKernelGGL(fused_mlp, dim3(ROWS / 64), dim3(512), 0, stream,
                       A, W1F, b1, W2, b2, outD, outW, ws + WS_EMB);

    const float* Dg  = outD;
    const float* Wgc = outW;
    void* args[] = { (void*)&Dg, (void*)&Wgc, (void*)&noise, (void*)&uinit,
                     (void*)&outE, (void*)&outX, (void*)&ws };
    (void)hipLaunchCooperativeKernel((const void*)coop_post, dim3(NB), dim3(NT),
                                     args, 0, stream);
}

// Round 14
// 848.971 us; speedup vs baseline: 1.0622x; 1.0622x over previous
//
#include <hip/hip_runtime.h>
#include <hip/hip_bf16.h>
#include <math.h>

#define NN 512
#define ROWS (NN * NN)
#define HH 512

#define NB 16                 // coop_post blocks
#define NT 512                // threads per block
#define RPB 32                // rows per block

// ws layout (float offsets)
#define WS_EMB   0                       // [4096] emb partials (one per fused_mlp block)
#define WS_COLP  4096                    // [NB*512] column partial sums
#define WS_U0    (WS_COLP + 32*512)      // [512]
#define WS_U1    (WS_U0 + 512)           // [512]
#define WS_X0    (WS_U1 + 512)           // [2048]
#define WS_X1    (WS_X0 + 2048)          // [2048]
#define WS_W1F   (WS_X1 + 2048)          // [131072] = 262144 bf16 (fragment-major W1)
#define WS_BAR   (WS_W1F + 131072)       // [512] ints: counter at [0]

typedef __attribute__((ext_vector_type(8))) short bf16x8;
typedef __attribute__((ext_vector_type(4))) float f32x4;

#define AGENT __HIP_MEMORY_SCOPE_AGENT

__device__ __forceinline__ short f2bf(float f) {   // RTNE (prep only)
    union { float f; unsigned u; } v; v.f = f;
    unsigned r = v.u + 0x7fffu + ((v.u >> 16) & 1u);
    return (short)(r >> 16);
}

// pack two fp32 -> two bf16 (truncation) in one v_perm_b32: bf(hi)<<16 | bf(lo)
__device__ __forceinline__ unsigned pack_bf2(float lo, float hi) {
    return __builtin_amdgcn_perm(__float_as_uint(hi), __float_as_uint(lo),
                                 0x07060302u);
}

__device__ __forceinline__ float softplus_f(float x) {
    return fmaxf(x, 0.0f) + log1pf(expf(-fabsf(x)));
}

__device__ __forceinline__ unsigned long long pk64(float a, float b) {
    return ((unsigned long long)__float_as_uint(b) << 32) |
           (unsigned long long)__float_as_uint(a);
}

// ---------------------------------------------------------------------------
// W1 (fp32 [k][n]) -> W1F fragment-major bf16 (wave B-frag = 1KB contiguous)
// ---------------------------------------------------------------------------
__global__ void w1f_prep(const float* __restrict__ W1, short* __restrict__ W1F)
{
    const int c = blockIdx.x * 256 + threadIdx.x;   // 0..32767
    const int lane = c & 63;
    const int g = c >> 6;
    const int colg = g & 31;
    const int kc = g >> 5;
    const int col = colg * 16 + (lane & 15);
    const int kb = kc * 32 + (lane >> 4) * 8;
    bf16x8 w;
    #pragma unroll
    for (int j = 0; j < 8; j++)
        w[j] = f2bf(W1[(size_t)(kb + j) * HH + col]);
    *(bf16x8*)(W1F + (size_t)c * 8) = w;
}

// ---------------------------------------------------------------------------
// Phase 1 (round-10 proven best): h = relu(A@W1+b1) via bf16 MFMA;
// fused epilogue -> D, W, emb parts. 4096 blocks x 512 thr; BM=64, BK=32.
// ---------------------------------------------------------------------------
__global__ __launch_bounds__(512, 4) void fused_mlp(
    const float* __restrict__ A, const short* __restrict__ W1F,
    const float* __restrict__ b1, const float* __restrict__ W2,
    const float* __restrict__ b2, float* __restrict__ outD,
    float* __restrict__ outW, float* __restrict__ embpart)
{
    __shared__ short As[2][64 * 40];
    __shared__ float sp0[8][64], sp1[8][64];
    __shared__ float semb[8];

    const int tid = threadIdx.x;
    const int lane = tid & 63;
    const int wc = tid >> 6;
    const int l15 = lane & 15;
    const int l4 = lane >> 4;
    const int row0 = blockIdx.x * 64;

    f32x4 acc[4][4];
    #pragma unroll
    for (int m = 0; m < 4; m++)
        #pragma unroll
        for (int n = 0; n < 4; n++) {
            f32x4 z = {0.0f, 0.0f, 0.0f, 0.0f};
            acc[m][n] = z;
        }

    const int sr = tid >> 3;
    const int sk4 = (tid & 7) * 4;
    const float* agp = A + (size_t)(row0 + sr) * HH + sk4;

    const short* bfp = W1F + ((size_t)(wc * 4) * 64 + lane) * 8;

    {
        float4 a0 = *(const float4*)agp;
        uint2 w = {pack_bf2(a0.x, a0.y), pack_bf2(a0.z, a0.w)};
        *(uint2*)&As[0][sr * 40 + sk4] = w;
    }
    __syncthreads();

    int cur = 0;
    #pragma unroll 1
    for (int s = 0; s < 16; s++) {
        const int k0 = s * 32;
        bf16x8 bfr[4];
        #pragma unroll
        for (int n = 0; n < 4; n++)
            bfr[n] = *(const bf16x8*)(bfp + s * 16384 + n * 512);
        float4 pv;
        if (s < 15) pv = *(const float4*)(agp + k0 + 32);
        bf16x8 af[4];
        #pragma unroll
        for (int m = 0; m < 4; m++)
            af[m] = *(const bf16x8*)&As[cur][(m * 16 + l15) * 40 + l4 * 8];
        #pragma unroll
        for (int m = 0; m < 4; m++)
            #pragma unroll
            for (int n = 0; n < 4; n++)
                acc[m][n] = __builtin_amdgcn_mfma_f32_16x16x32_bf16(
                    af[m], bfr[n], acc[m][n], 0, 0, 0);
        if (s < 15) {
            uint2 w = {pack_bf2(pv.x, pv.y), pack_bf2(pv.z, pv.w)};
            *(uint2*)&As[cur ^ 1][sr * 40 + sk4] = w;
        }
        __syncthreads();
        cur ^= 1;
    }

    float b1c[4], w20[4], w21[4];
    #pragma unroll
    for (int n = 0; n < 4; n++) {
        int col = wc * 64 + n * 16 + l15;
        b1c[n] = b1[col];
        w20[n] = W2[col * 2 + 0];
        w21[n] = W2[col * 2 + 1];
    }
    float embl = 0.0f;
    #pragma unroll
    for (int m = 0; m < 4; m++) {
        #pragma unroll
        for (int j = 0; j < 4; j++) {
            float s0 = 0.0f, s1 = 0.0f;
            #pragma unroll
            for (int n = 0; n < 4; n++) {
                float h = fmaxf(acc[m][n][j] + b1c[n], 0.0f);
                s0 = fmaf(h, w20[n], s0);
                s1 = fmaf(h, w21[n], s1);
                embl += h;
            }
            #pragma unroll
            for (int st = 1; st < 16; st <<= 1) {
                s0 += __shfl_xor(s0, st);
                s1 += __shfl_xor(s1, st);
            }
            if (l15 == 0) {
                int row = m * 16 + l4 * 4 + j;
                sp0[wc][row] = s0;
                sp1[wc][row] = s1;
            }
        }
    }
    #pragma unroll
    for (int st = 1; st < 64; st <<= 1) embl += __shfl_xor(embl, st);
    if (lane == 0) semb[wc] = embl;
    __syncthreads();
    if (tid < 64) {
        int gr = row0 + tid;
        float p0 = b2[0], p1 = b2[1];
        #pragma unroll
        for (int w = 0; w < 8; w++) { p0 += sp0[w][tid]; p1 += sp1[w][tid]; }
        int di = gr >> 9, dj = gr & 511;
        outD[gr] = (di == dj) ? 0.0f : softplus_f(p0);
        outW[gr] = softplus_f(p1);
    }
    if (tid == 0) {
        float e = 0.0f;
        #pragma unroll
        for (int w = 0; w < 8; w++) e += semb[w];
        embpart[blockIdx.x] = e;
    }
}

// ---------------------------------------------------------------------------
// counter grid barrier (proven round-5/8/10): one memory-side atomic add per block
// ---------------------------------------------------------------------------
__device__ __forceinline__ void gbar(int* cnt, int target)
{
    __syncthreads();
    if (threadIdx.x == 0)
        __hip_atomic_fetch_add(cnt, 1, __ATOMIC_RELAXED, AGENT);
    if (threadIdx.x < 64) {
        while (__hip_atomic_load(cnt, __ATOMIC_RELAXED, AGENT) < target)
            __builtin_amdgcn_s_sleep(1);
    }
    __syncthreads();
}

__device__ __forceinline__ void block_sum5(float* v, float (*red)[8], int tid) {
    #pragma unroll
    for (int s = 1; s < 64; s <<= 1)
        #pragma unroll
        for (int q = 0; q < 5; q++) v[q] += __shfl_xor(v[q], s);
    if ((tid & 63) == 0)
        #pragma unroll
        for (int q = 0; q < 5; q++) red[q][tid >> 6] = v[q];
    __syncthreads();
    #pragma unroll
    for (int q = 0; q < 5; q++) {
        float r = 0.0f;
        #pragma unroll
        for (int i = 0; i < 8; i++) r += red[q][i];
        v[q] = r;
    }
    __syncthreads();
}

__device__ __forceinline__ float block_sum1(float v, float (*red)[8], int tid) {
    #pragma unroll
    for (int s = 1; s < 64; s <<= 1) v += __shfl_xor(v, s);
    if ((tid & 63) == 0) red[0][tid >> 6] = v;
    __syncthreads();
    float r = 0.0f;
    #pragma unroll
    for (int i = 0; i < 8; i++) r += red[0][i];
    __syncthreads();
    return r;
}

// ---------------------------------------------------------------------------
// Phases 2-4: NB=16 blocks x NT=512 threads, RPB=32 rows/block.
// Phase 4: (S1,S2) packed as one bf16-pair uint in Dl (in-place), X read b128.
// ---------------------------------------------------------------------------
__global__ __launch_bounds__(512, 1) void coop_post(
    const float* __restrict__ Dg, const float* __restrict__ Wg,
    const float* __restrict__ noise, const float* __restrict__ uinit,
    float* __restrict__ outE, float* __restrict__ outX,
    float* __restrict__ ws)
{
    __shared__ float Dl[RPB][516];     // phase3: D rows fp32; phase4: packed (s1,s2)
    __shared__ float Xl[512][4];
    __shared__ float ul[512];
    __shared__ float upl[3][512];
    __shared__ float cm[512];
    __shared__ float rm[RPB];
    __shared__ float red5[5][8];

    const int tid = threadIdx.x;
    const int bid = blockIdx.x;
    const int r0 = bid * RPB;

    float* embpart = ws + WS_EMB;
    float* colpart = ws + WS_COLP;
    float* ubuf0   = ws + WS_U0;
    float* ubuf1   = ws + WS_U1;
    float* Xg0     = ws + WS_X0;
    float* Xg1     = ws + WS_X1;
    int* cnt       = (int*)(ws + WS_BAR);
    int bg = 0;

    // ---- phase 2a: load D rows, row means, column partial sums
    for (int idx = tid; idx < RPB * 512; idx += NT) {
        int r = idx >> 9, c = idx & 511;
        Dl[r][c] = Dg[(size_t)(r0 + r) * NN + c];
    }
    __syncthreads();
    const int mr = tid >> 4;           // 0..31
    const int ml = tid & 15;
    {
        float s = 0.0f;
        for (int j = ml; j < 512; j += 16) s += Dl[mr][j];
        #pragma unroll
        for (int st = 1; st < 16; st <<= 1) s += __shfl_xor(s, st);
        if (ml == 0) rm[mr] = s * (1.0f / 512.0f);
    }
    {
        float s = 0.0f;
        #pragma unroll
        for (int r = 0; r < RPB; r++) s += Dl[r][tid];
        __hip_atomic_store(&colpart[bid * 512 + tid], s, __ATOMIC_RELAXED, AGENT);
    }
    gbar(cnt, NB * ++bg);

    // ---- phase 2b: column means into LDS (redundant); emb total (block 0)
    {
        float s = 0.0f;
        #pragma unroll
        for (int p = 0; p < NB; p++)
            s += __hip_atomic_load(&colpart[p * 512 + tid], __ATOMIC_RELAXED, AGENT);
        cm[tid] = s * (1.0f / 512.0f);
    }
    if (bid == 0) {
        float s = 0.0f;
        for (int i = tid; i < ROWS / 64; i += NT) s += embpart[i];
        s = block_sum1(s, red5, tid);
        if (tid == 0) outE[0] = s;
    }
    __syncthreads();
    float Dmean = block_sum1(cm[tid], red5, tid) * (1.0f / 512.0f);

    // ---- phase 3: power iteration with implicit deflation
    int cur = 0;
    #pragma unroll 1
    for (int rank = 0; rank < 3; rank++) {
        #pragma unroll 1
        for (int step = 0; step < 10; step++) {
            if (step == 0) {
                ul[tid] = uinit[tid * 3 + rank];
            } else {
                const float* ub = cur ? ubuf1 : ubuf0;
                ul[tid] = __hip_atomic_load(&ub[tid], __ATOMIC_RELAXED, AGENT);
            }
            __syncthreads();
            float u = ul[tid];
            float v[5];
            v[0] = u * u;
            v[1] = u;
            v[2] = cm[tid] * u;
            v[3] = (rank > 0) ? upl[0][tid] * u : 0.0f;
            v[4] = (rank > 1) ? upl[1][tid] * u : 0.0f;
            block_sum5(v, red5, tid);
            float inv = 1.0f / fmaxf(sqrtf(v[0]), 0.001f);
            float S = v[1] * inv, dr = v[2] * inv;
            float d0s = v[3] * inv, d1s = v[4] * inv;
            float a = 0.0f;
            for (int j = ml; j < 512; j += 16) a = fmaf(Dl[mr][j], ul[j], a);
            #pragma unroll
            for (int st = 1; st < 16; st <<= 1) a += __shfl_xor(a, st);
            if (ml == 0) {
                float bvv = -0.5f * (a * inv - dr - rm[mr] * S + Dmean * S);
                if (rank > 0) bvv -= d0s * upl[0][r0 + mr];
                if (rank > 1) bvv -= d1s * upl[1][r0 + mr];
                float* ubn = cur ? ubuf0 : ubuf1;
                __hip_atomic_store(&ubn[r0 + mr], bvv, __ATOMIC_RELAXED, AGENT);
            }
            gbar(cnt, NB * ++bg);
            cur ^= 1;
        }
        // finalize rank (fully local: each block holds/reads the full u)
        {
            const float* ub = cur ? ubuf1 : ubuf0;
            float u = __hip_atomic_load(&ub[tid], __ATOMIC_RELAXED, AGENT);
            float eig2 = block_sum1(u * u, red5, tid);
            float scl = sqrtf(sqrtf(eig2 + 0.01f));
            upl[rank][tid] = u * scl;
            Xl[tid][rank] = fmaf(u, scl, noise[tid * 3 + rank]);
            if (rank == 0) Xl[tid][3] = 0.0f;
            __syncthreads();
        }
    }

    // ---- phase 4 prep: pack (s1 = W+W^T, s2 = W.D+(W.D)^T) as bf16 pair,
    //      in-place over Dl (each slot read+written by the same thread)
    for (int idx = tid; idx < RPB * 512; idx += NT) {
        int r = idx >> 9, j = idx & 511;
        int gr = r0 + r;
        float wr = Wg[(size_t)gr * NN + j];
        float wc = Wg[(size_t)j * NN + gr];
        float dc = Dg[(size_t)j * NN + gr];
        float d  = Dl[r][j];
        *(unsigned*)&Dl[r][j] = pack_bf2(wr + wc, fmaf(wr, d, wc * dc));
    }
    __syncthreads();

    // ---- phase 4: 100 gradient-flow steps (packed S-word + b128 X reads)
    unsigned long long* X064 = (unsigned long long*)Xg0;
    unsigned long long* X164 = (unsigned long long*)Xg1;
    int par = 0;
    #pragma unroll 1
    for (int t = 0; t < 100; t++) {
        float xr0 = Xl[r0 + mr][0], xr1 = Xl[r0 + mr][1], xr2 = Xl[r0 + mr][2];
        const unsigned* sprow = (const unsigned*)&Dl[mr][0];
        float g0 = 0, g1 = 0, g2 = 0;
        for (int j = ml; j < 512; j += 16) {
            float4 xj = *(const float4*)&Xl[j][0];
            float dx0 = xr0 - xj.x;
            float dx1 = xr1 - xj.y;
            float dx2 = xr2 - xj.z;
            float d2 = fmaf(dx0, dx0, fmaf(dx1, dx1, fmaf(dx2, dx2, 0.01f)));
            float ri = rsqrtf(d2);
            unsigned pv = sprow[j];
            float s1 = __uint_as_float(pv << 16);
            float s2 = __uint_as_float(pv & 0xffff0000u);
            float coef = fmaf(s2, ri, -s1);
            g0 = fmaf(coef, dx0, g0);
            g1 = fmaf(coef, dx1, g1);
            g2 = fmaf(coef, dx2, g2);
        }
        #pragma unroll
        for (int st = 1; st < 16; st <<= 1) {
            g0 += __shfl_xor(g0, st);
            g1 += __shfl_xor(g1, st);
            g2 += __shfl_xor(g2, st);
        }
        if (ml == 0) {
            float dX0 = 0.2f * g0, dX1 = 0.2f * g1, dX2 = 0.2f * g2;
            float sp = sqrtf(fmaf(dX0, dX0, fmaf(dX1, dX1, fmaf(dX2, dX2, 0.001f))));
            float alpha = 0.1f + 4.9f * (float)(100 - t) * 0.01f;
            float scal = alpha * tanhf(sp / alpha) / sp;
            float n0 = fmaf(dX0, scal, xr0);
            float n1 = fmaf(dX1, scal, xr1);
            float n2 = fmaf(dX2, scal, xr2);
            int gr = r0 + mr;
            if (t == 99) {
                outX[gr * 3 + 0] = n0;
                outX[gr * 3 + 1] = n1;
                outX[gr * 3 + 2] = n2;
            } else {
                unsigned long long* Xd64 = par ? X164 : X064;
                __hip_atomic_store(&Xd64[gr * 2], pk64(n0, n1),
                                   __ATOMIC_RELAXED, AGENT);
                __hip_atomic_store(&Xd64[gr * 2 + 1], pk64(n2, 0.0f),
                                   __ATOMIC_RELAXED, AGENT);
            }
        }
        if (t == 99) break;
        gbar(cnt, NB * ++bg);
        {
            const unsigned long long* Xs64 = par ? X164 : X064;
            unsigned long long lo =
                __hip_atomic_load(&Xs64[tid * 2], __ATOMIC_RELAXED, AGENT);
            unsigned long long hi =
                __hip_atomic_load(&Xs64[tid * 2 + 1], __ATOMIC_RELAXED, AGENT);
            Xl[tid][0] = __uint_as_float((unsigned)lo);
            Xl[tid][1] = __uint_as_float((unsigned)(lo >> 32));
            Xl[tid][2] = __uint_as_float((unsigned)hi);
            Xl[tid][3] = 0.0f;
        }
        __syncthreads();
        par ^= 1;
    }
}

extern "C" void kernel_launch(void* const* d_in, const int* in_sizes, int n_in,
                              void* d_out, int out_size, void* d_ws, size_t ws_size,
                              hipStream_t stream)
{
    const float* A     = (const float*)d_in[0];
    const float* W1    = (const float*)d_in[1];
    const float* b1    = (const float*)d_in[2];
    const float* W2    = (const float*)d_in[3];
    const float* b2    = (const float*)d_in[4];
    const float* noise = (const float*)d_in[5];
    const float* uinit = (const float*)d_in[6];

    float* out  = (float*)d_out;
    float* outD = out;
    float* outW = out + ROWS;
    float* outE = out + 2 * ROWS;
    float* outX = out + 2 * ROWS + 1;
    float* ws   = (float*)d_ws;
    short* W1F  = (short*)(ws + WS_W1F);

    // reset barrier counter every call (graph replays reuse ws)
    (void)hipMemsetAsync((char*)d_ws + (size_t)WS_BAR * sizeof(float), 0,
                         512 * sizeof(int), stream);

    hipLaunchKernelGGL(w1f_prep, dim3(128), dim3(256), 0, stream, W1, W1F);

    hipLaunchKernelGGL(fused_mlp, dim3(ROWS / 64), dim3(512), 0, stream,
                       A, W1F, b1, W2, b2, outD, outW, ws + WS_EMB);

    const float* Dg  = outD;
    const float* Wgc = outW;
    void* args[] = { (void*)&Dg, (void*)&Wgc, (void*)&noise, (void*)&uinit,
                     (void*)&outE, (void*)&outX, (void*)&ws };
    (void)hipLaunchCooperativeKernel((const void*)coop_post, dim3(NB), dim3(NT),
                                     args, 0, stream);
}

// Round 15
// 836.728 us; speedup vs baseline: 1.0777x; 1.0146x over previous
//
#include <hip/hip_runtime.h>
#include <hip/hip_bf16.h>
#include <math.h>

#define NN 512
#define ROWS (NN * NN)
#define HH 512

#define NB 16                 // coop_post blocks
#define NT 512                // threads per block
#define RPB 32                // rows per block

// ws layout (float offsets)
#define WS_EMB   0                       // [4096] emb partials (one per fused_mlp block)
#define WS_COLP  4096                    // [NB*512] column partial sums
#define WS_U0    (WS_COLP + 32*512)      // [512]
#define WS_U1    (WS_U0 + 512)           // [512]
#define WS_X0    (WS_U1 + 512)           // [2048]
#define WS_X1    (WS_X0 + 2048)          // [2048]
#define WS_W1F   (WS_X1 + 2048)          // [131072] = 262144 bf16 (fragment-major W1)
#define WS_BAR   (WS_W1F + 131072)       // [512] ints: counter at [0]

typedef __attribute__((ext_vector_type(8))) short bf16x8;
typedef __attribute__((ext_vector_type(4))) float f32x4;

#define AGENT __HIP_MEMORY_SCOPE_AGENT

__device__ __forceinline__ short f2bf(float f) {   // RTNE (prep only)
    union { float f; unsigned u; } v; v.f = f;
    unsigned r = v.u + 0x7fffu + ((v.u >> 16) & 1u);
    return (short)(r >> 16);
}

// pack two fp32 -> two bf16 (truncation) in one v_perm_b32: bf(hi)<<16 | bf(lo)
__device__ __forceinline__ unsigned pack_bf2(float lo, float hi) {
    return __builtin_amdgcn_perm(__float_as_uint(hi), __float_as_uint(lo),
                                 0x07060302u);
}

__device__ __forceinline__ float softplus_f(float x) {
    return fmaxf(x, 0.0f) + log1pf(expf(-fabsf(x)));
}

__device__ __forceinline__ unsigned long long pk64(float a, float b) {
    return ((unsigned long long)__float_as_uint(b) << 32) |
           (unsigned long long)__float_as_uint(a);
}

// ---------------------------------------------------------------------------
// W1 (fp32 [k][n]) -> W1F fragment-major bf16 (wave B-frag = 1KB contiguous)
// ---------------------------------------------------------------------------
__global__ void w1f_prep(const float* __restrict__ W1, short* __restrict__ W1F)
{
    const int c = blockIdx.x * 256 + threadIdx.x;   // 0..32767
    const int lane = c & 63;
    const int g = c >> 6;
    const int colg = g & 31;
    const int kc = g >> 5;
    const int col = colg * 16 + (lane & 15);
    const int kb = kc * 32 + (lane >> 4) * 8;
    bf16x8 w;
    #pragma unroll
    for (int j = 0; j < 8; j++)
        w[j] = f2bf(W1[(size_t)(kb + j) * HH + col]);
    *(bf16x8*)(W1F + (size_t)c * 8) = w;
}

// ---------------------------------------------------------------------------
// Phase 1: h = relu(A@W1+b1) via bf16 MFMA; fused epilogue -> D, W, emb parts
// 4096 blocks x 512 thr; BM=64, BN=512.
// FULL A-strip (64x512 bf16, 66.6KB LDS) staged ONCE -> K-loop has ZERO
// barriers; waves pipeline B-L2 loads freely across all 16 iterations.
// ---------------------------------------------------------------------------
__global__ __launch_bounds__(512, 4) void fused_mlp(
    const float* __restrict__ A, const short* __restrict__ W1F,
    const float* __restrict__ b1, const float* __restrict__ W2,
    const float* __restrict__ b2, float* __restrict__ outD,
    float* __restrict__ outW, float* __restrict__ embpart)
{
    __shared__ short As[64][520];          // 66.6 KB, pad 512->520 (2-way-free)
    __shared__ float sp0[8][64], sp1[8][64];
    __shared__ float semb[8];

    const int tid = threadIdx.x;
    const int lane = tid & 63;
    const int wc = tid >> 6;               // wave id = column group 0..7
    const int l15 = lane & 15;
    const int l4 = lane >> 4;
    const int row0 = blockIdx.x * 64;

    f32x4 acc[4][4];
    #pragma unroll
    for (int m = 0; m < 4; m++)
        #pragma unroll
        for (int n = 0; n < 4; n++) {
            f32x4 z = {0.0f, 0.0f, 0.0f, 0.0f};
            acc[m][n] = z;
        }

    // ---- stage the FULL 64x512 A-strip once (16 coalesced float4 per thread)
    {
        const int sr = tid >> 3;           // row 0..63
        const int sk = (tid & 7) * 4;      // k offset within each 32-wide pass
        const float* agp = A + (size_t)(row0 + sr) * HH + sk;
        #pragma unroll
        for (int i = 0; i < 16; i++) {
            float4 a = *(const float4*)(agp + i * 32);
            uint2 w = {pack_bf2(a.x, a.y), pack_bf2(a.z, a.w)};
            *(uint2*)&As[sr][sk + i * 32] = w;
        }
    }
    __syncthreads();

    // ---- barrier-free K-loop
    const short* bfp = W1F + ((size_t)(wc * 4) * 64 + lane) * 8;
    #pragma unroll 1
    for (int s = 0; s < 16; s++) {
        bf16x8 bfr[4];
        #pragma unroll
        for (int n = 0; n < 4; n++)
            bfr[n] = *(const bf16x8*)(bfp + s * 16384 + n * 512);
        bf16x8 af[4];
        #pragma unroll
        for (int m = 0; m < 4; m++)
            af[m] = *(const bf16x8*)&As[m * 16 + l15][s * 32 + l4 * 8];
        #pragma unroll
        for (int m = 0; m < 4; m++)
            #pragma unroll
            for (int n = 0; n < 4; n++)
                acc[m][n] = __builtin_amdgcn_mfma_f32_16x16x32_bf16(
                    af[m], bfr[n], acc[m][n], 0, 0, 0);
    }

    // ---- epilogue: bias+relu, dot with W2 cols, emb partial
    float b1c[4], w20[4], w21[4];
    #pragma unroll
    for (int n = 0; n < 4; n++) {
        int col = wc * 64 + n * 16 + l15;
        b1c[n] = b1[col];
        w20[n] = W2[col * 2 + 0];
        w21[n] = W2[col * 2 + 1];
    }
    float embl = 0.0f;
    #pragma unroll
    for (int m = 0; m < 4; m++) {
        #pragma unroll
        for (int j = 0; j < 4; j++) {
            float s0 = 0.0f, s1 = 0.0f;
            #pragma unroll
            for (int n = 0; n < 4; n++) {
                float h = fmaxf(acc[m][n][j] + b1c[n], 0.0f);
                s0 = fmaf(h, w20[n], s0);
                s1 = fmaf(h, w21[n], s1);
                embl += h;
            }
            #pragma unroll
            for (int st = 1; st < 16; st <<= 1) {
                s0 += __shfl_xor(s0, st);
                s1 += __shfl_xor(s1, st);
            }
            if (l15 == 0) {
                int row = m * 16 + l4 * 4 + j;
                sp0[wc][row] = s0;
                sp1[wc][row] = s1;
            }
        }
    }
    #pragma unroll
    for (int st = 1; st < 64; st <<= 1) embl += __shfl_xor(embl, st);
    if (lane == 0) semb[wc] = embl;
    __syncthreads();
    if (tid < 64) {
        int gr = row0 + tid;
        float p0 = b2[0], p1 = b2[1];
        #pragma unroll
        for (int w = 0; w < 8; w++) { p0 += sp0[w][tid]; p1 += sp1[w][tid]; }
        int di = gr >> 9, dj = gr & 511;
        outD[gr] = (di == dj) ? 0.0f : softplus_f(p0);
        outW[gr] = softplus_f(p1);
    }
    if (tid == 0) {
        float e = 0.0f;
        #pragma unroll
        for (int w = 0; w < 8; w++) e += semb[w];
        embpart[blockIdx.x] = e;
    }
}

// ---------------------------------------------------------------------------
// counter grid barrier (proven round-5/8/10): one memory-side atomic add per block
// ---------------------------------------------------------------------------
__device__ __forceinline__ void gbar(int* cnt, int target)
{
    __syncthreads();
    if (threadIdx.x == 0)
        __hip_atomic_fetch_add(cnt, 1, __ATOMIC_RELAXED, AGENT);
    if (threadIdx.x < 64) {
        while (__hip_atomic_load(cnt, __ATOMIC_RELAXED, AGENT) < target)
            __builtin_amdgcn_s_sleep(1);
    }
    __syncthreads();
}

__device__ __forceinline__ void block_sum5(float* v, float (*red)[8], int tid) {
    #pragma unroll
    for (int s = 1; s < 64; s <<= 1)
        #pragma unroll
        for (int q = 0; q < 5; q++) v[q] += __shfl_xor(v[q], s);
    if ((tid & 63) == 0)
        #pragma unroll
        for (int q = 0; q < 5; q++) red[q][tid >> 6] = v[q];
    __syncthreads();
    #pragma unroll
    for (int q = 0; q < 5; q++) {
        float r = 0.0f;
        #pragma unroll
        for (int i = 0; i < 8; i++) r += red[q][i];
        v[q] = r;
    }
    __syncthreads();
}

__device__ __forceinline__ float block_sum1(float v, float (*red)[8], int tid) {
    #pragma unroll
    for (int s = 1; s < 64; s <<= 1) v += __shfl_xor(v, s);
    if ((tid & 63) == 0) red[0][tid >> 6] = v;
    __syncthreads();
    float r = 0.0f;
    #pragma unroll
    for (int i = 0; i < 8; i++) r += red[0][i];
    __syncthreads();
    return r;
}

// ---------------------------------------------------------------------------
// Phases 2-4 (round-14 proven): NB=16 x NT=512, RPB=32 rows/block.
// Phase 4: (S1,S2) packed as one bf16-pair uint in Dl (in-place), X read b128.
// ---------------------------------------------------------------------------
__global__ __launch_bounds__(512, 1) void coop_post(
    const float* __restrict__ Dg, const float* __restrict__ Wg,
    const float* __restrict__ noise, const float* __restrict__ uinit,
    float* __restrict__ outE, float* __restrict__ outX,
    float* __restrict__ ws)
{
    __shared__ float Dl[RPB][516];     // phase3: D rows fp32; phase4: packed (s1,s2)
    __shared__ float Xl[512][4];
    __shared__ float ul[512];
    __shared__ float upl[3][512];
    __shared__ float cm[512];
    __shared__ float rm[RPB];
    __shared__ float red5[5][8];

    const int tid = threadIdx.x;
    const int bid = blockIdx.x;
    const int r0 = bid * RPB;

    float* embpart = ws + WS_EMB;
    float* colpart = ws + WS_COLP;
    float* ubuf0   = ws + WS_U0;
    float* ubuf1   = ws + WS_U1;
    float* Xg0     = ws + WS_X0;
    float* Xg1     = ws + WS_X1;
    int* cnt       = (int*)(ws + WS_BAR);
    int bg = 0;

    // ---- phase 2a: load D rows, row means, column partial sums
    for (int idx = tid; idx < RPB * 512; idx += NT) {
        int r = idx >> 9, c = idx & 511;
        Dl[r][c] = Dg[(size_t)(r0 + r) * NN + c];
    }
    __syncthreads();
    const int mr = tid >> 4;           // 0..31
    const int ml = tid & 15;
    {
        float s = 0.0f;
        for (int j = ml; j < 512; j += 16) s += Dl[mr][j];
        #pragma unroll
        for (int st = 1; st < 16; st <<= 1) s += __shfl_xor(s, st);
        if (ml == 0) rm[mr] = s * (1.0f / 512.0f);
    }
    {
        float s = 0.0f;
        #pragma unroll
        for (int r = 0; r < RPB; r++) s += Dl[r][tid];
        __hip_atomic_store(&colpart[bid * 512 + tid], s, __ATOMIC_RELAXED, AGENT);
    }
    gbar(cnt, NB * ++bg);

    // ---- phase 2b: column means into LDS (redundant); emb total (block 0)
    {
        float s = 0.0f;
        #pragma unroll
        for (int p = 0; p < NB; p++)
            s += __hip_atomic_load(&colpart[p * 512 + tid], __ATOMIC_RELAXED, AGENT);
        cm[tid] = s * (1.0f / 512.0f);
    }
    if (bid == 0) {
        float s = 0.0f;
        for (int i = tid; i < ROWS / 64; i += NT) s += embpart[i];
        s = block_sum1(s, red5, tid);
        if (tid == 0) outE[0] = s;
    }
    __syncthreads();
    float Dmean = block_sum1(cm[tid], red5, tid) * (1.0f / 512.0f);

    // ---- phase 3: power iteration with implicit deflation
    int cur = 0;
    #pragma unroll 1
    for (int rank = 0; rank < 3; rank++) {
        #pragma unroll 1
        for (int step = 0; step < 10; step++) {
            if (step == 0) {
                ul[tid] = uinit[tid * 3 + rank];
            } else {
                const float* ub = cur ? ubuf1 : ubuf0;
                ul[tid] = __hip_atomic_load(&ub[tid], __ATOMIC_RELAXED, AGENT);
            }
            __syncthreads();
            float u = ul[tid];
            float v[5];
            v[0] = u * u;
            v[1] = u;
            v[2] = cm[tid] * u;
            v[3] = (rank > 0) ? upl[0][tid] * u : 0.0f;
            v[4] = (rank > 1) ? upl[1][tid] * u : 0.0f;
            block_sum5(v, red5, tid);
            float inv = 1.0f / fmaxf(sqrtf(v[0]), 0.001f);
            float S = v[1] * inv, dr = v[2] * inv;
            float d0s = v[3] * inv, d1s = v[4] * inv;
            float a = 0.0f;
            for (int j = ml; j < 512; j += 16) a = fmaf(Dl[mr][j], ul[j], a);
            #pragma unroll
            for (int st = 1; st < 16; st <<= 1) a += __shfl_xor(a, st);
            if (ml == 0) {
                float bvv = -0.5f * (a * inv - dr - rm[mr] * S + Dmean * S);
                if (rank > 0) bvv -= d0s * upl[0][r0 + mr];
                if (rank > 1) bvv -= d1s * upl[1][r0 + mr];
                float* ubn = cur ? ubuf0 : ubuf1;
                __hip_atomic_store(&ubn[r0 + mr], bvv, __ATOMIC_RELAXED, AGENT);
            }
            gbar(cnt, NB * ++bg);
            cur ^= 1;
        }
        // finalize rank (fully local: each block holds/reads the full u)
        {
            const float* ub = cur ? ubuf1 : ubuf0;
            float u = __hip_atomic_load(&ub[tid], __ATOMIC_RELAXED, AGENT);
            float eig2 = block_sum1(u * u, red5, tid);
            float scl = sqrtf(sqrtf(eig2 + 0.01f));
            upl[rank][tid] = u * scl;
            Xl[tid][rank] = fmaf(u, scl, noise[tid * 3 + rank]);
            if (rank == 0) Xl[tid][3] = 0.0f;
            __syncthreads();
        }
    }

    // ---- phase 4 prep: pack (s1 = W+W^T, s2 = W.D+(W.D)^T) as bf16 pair,
    //      in-place over Dl (each slot read+written by the same thread)
    for (int idx = tid; idx < RPB * 512; idx += NT) {
        int r = idx >> 9, j = idx & 511;
        int gr = r0 + r;
        float wr = Wg[(size_t)gr * NN + j];
        float wc = Wg[(size_t)j * NN + gr];
        float dc = Dg[(size_t)j * NN + gr];
        float d  = Dl[r][j];
        *(unsigned*)&Dl[r][j] = pack_bf2(wr + wc, fmaf(wr, d, wc * dc));
    }
    __syncthreads();

    // ---- phase 4: 100 gradient-flow steps (packed S-word + b128 X reads)
    unsigned long long* X064 = (unsigned long long*)Xg0;
    unsigned long long* X164 = (unsigned long long*)Xg1;
    int par = 0;
    #pragma unroll 1
    for (int t = 0; t < 100; t++) {
        float xr0 = Xl[r0 + mr][0], xr1 = Xl[r0 + mr][1], xr2 = Xl[r0 + mr][2];
        const unsigned* sprow = (const unsigned*)&Dl[mr][0];
        float g0 = 0, g1 = 0, g2 = 0;
        for (int j = ml; j < 512; j += 16) {
            float4 xj = *(const float4*)&Xl[j][0];
            float dx0 = xr0 - xj.x;
            float dx1 = xr1 - xj.y;
            float dx2 = xr2 - xj.z;
            float d2 = fmaf(dx0, dx0, fmaf(dx1, dx1, fmaf(dx2, dx2, 0.01f)));
            float ri = rsqrtf(d2);
            unsigned pv = sprow[j];
            float s1 = __uint_as_float(pv << 16);
            float s2 = __uint_as_float(pv & 0xffff0000u);
            float coef = fmaf(s2, ri, -s1);
            g0 = fmaf(coef, dx0, g0);
            g1 = fmaf(coef, dx1, g1);
            g2 = fmaf(coef, dx2, g2);
        }
        #pragma unroll
        for (int st = 1; st < 16; st <<= 1) {
            g0 += __shfl_xor(g0, st);
            g1 += __shfl_xor(g1, st);
            g2 += __shfl_xor(g2, st);
        }
        if (ml == 0) {
            float dX0 = 0.2f * g0, dX1 = 0.2f * g1, dX2 = 0.2f * g2;
            float sp = sqrtf(fmaf(dX0, dX0, fmaf(dX1, dX1, fmaf(dX2, dX2, 0.001f))));
            float alpha = 0.1f + 4.9f * (float)(100 - t) * 0.01f;
            float scal = alpha * tanhf(sp / alpha) / sp;
            float n0 = fmaf(dX0, scal, xr0);
            float n1 = fmaf(dX1, scal, xr1);
            float n2 = fmaf(dX2, scal, xr2);
            int gr = r0 + mr;
            if (t == 99) {
                outX[gr * 3 + 0] = n0;
                outX[gr * 3 + 1] = n1;
                outX[gr * 3 + 2] = n2;
            } else {
                unsigned long long* Xd64 = par ? X164 : X064;
                __hip_atomic_store(&Xd64[gr * 2], pk64(n0, n1),
                                   __ATOMIC_RELAXED, AGENT);
                __hip_atomic_store(&Xd64[gr * 2 + 1], pk64(n2, 0.0f),
                                   __ATOMIC_RELAXED, AGENT);
            }
        }
        if (t == 99) break;
        gbar(cnt, NB * ++bg);
        {
            const unsigned long long* Xs64 = par ? X164 : X064;
            unsigned long long lo =
                __hip_atomic_load(&Xs64[tid * 2], __ATOMIC_RELAXED, AGENT);
            unsigned long long hi =
                __hip_atomic_load(&Xs64[tid * 2 + 1], __ATOMIC_RELAXED, AGENT);
            Xl[tid][0] = __uint_as_float((unsigned)lo);
            Xl[tid][1] = __uint_as_float((unsigned)(lo >> 32));
            Xl[tid][2] = __uint_as_float((unsigned)hi);
            Xl[tid][3] = 0.0f;
        }
        __syncthreads();
        par ^= 1;
    }
}

extern "C" void kernel_launch(void* const* d_in, const int* in_sizes, int n_in,
                              void* d_out, int out_size, void* d_ws, size_t ws_size,
                              hipStream_t stream)
{
    const float* A     = (const float*)d_in[0];
    const float* W1    = (const float*)d_in[1];
    const float* b1    = (const float*)d_in[2];
    const float* W2    = (const float*)d_in[3];
    const float* b2    = (const float*)d_in[4];
    const float* noise = (const float*)d_in[5];
    const float* uinit = (const float*)d_in[6];

    float* out  = (float*)d_out;
    float* outD = out;
    float* outW = out + ROWS;
    float* outE = out + 2 * ROWS;
    float* outX = out + 2 * ROWS + 1;
    float* ws   = (float*)d_ws;
    short* W1F  = (short*)(ws + WS_W1F);

    // reset barrier counter every call (graph replays reuse ws)
    (void)hipMemsetAsync((char*)d_ws + (size_t)WS_BAR * sizeof(float), 0,
                         512 * sizeof(int), stream);

    hipLaunchKernelGGL(w1f_prep, dim3(128), dim3(256), 0, stream, W1, W1F);

    hipLaunchKernelGGL(fused_mlp, dim3(ROWS / 64), dim3(512), 0, stream,
                       A, W1F, b1, W2, b2, outD, outW, ws + WS_EMB);

    const float* Dg  = outD;
    const float* Wgc = outW;
    void* args[] = { (void*)&Dg, (void*)&Wgc, (void*)&noise, (void*)&uinit,
                     (void*)&outE, (void*)&outX, (void*)&ws };
    (void)hipLaunchCooperativeKernel((const void*)coop_post, dim3(NB), dim3(NT),
                                     args, 0, stream);
}